// Round 11
// baseline (71.481 us; speedup 1.0000x reference)
//
#include <hip/hip_runtime.h>
#include <math.h>

// ---------------------------------------------------------------------------
// QCNN 8-qubit statevector, v11: T in lane-distributed VGPRs (readlane).
//   K1 qcnn_eval_grid: in-block param setup + 3^8 grid eval; writes g_R in
//      ROLE-MAJOR order: role = tt*6 + t3*2 + bh (12 roles x 1152 floats),
//      positions enumerated exactly as contract<BH> walks them.
//   K2 qcnn_apply: each role-wave loads its <=1134-float T slice into 18
//      lane-distributed VGPRs (18 coalesced dwords), then the contraction is
//      pure VALU: v_readlane (compile-time reg+lane) -> SGPR -> FMA.
//      No memory ops in the hot loop at all. 12 role-waves, E=4.
// ---------------------------------------------------------------------------

__device__ float g_R[13824];   // 12 roles x 1152

struct c32 { float x, y; };
__device__ __forceinline__ c32 cmul(c32 a, c32 b){ return c32{a.x*b.x - a.y*b.y, a.x*b.y + a.y*b.x}; }
__device__ __forceinline__ c32 cadd(c32 a, c32 b){ return c32{a.x+b.x, a.y+b.y}; }
__device__ __forceinline__ c32 csel(bool c, c32 a, c32 b){ return c32{c?a.x:b.x, c?a.y:b.y}; }

struct PP { float a, b, c, d; };

__device__ __forceinline__ float pget(int i, PP pp) {
    float s = (i < 64) ? pp.a : (i < 128) ? pp.b : (i < 192) ? pp.c : pp.d;
    return __uint_as_float(__builtin_amdgcn_readlane(__float_as_uint(s), i & 63));
}
#define P(I) pget((I), pp)

template<int M>
__device__ __forceinline__ float sx(float v) {
    if constexpr (M == 1) {
        return __int_as_float(__builtin_amdgcn_update_dpp(
            __float_as_int(v), __float_as_int(v), 0xB1, 0xF, 0xF, false));
    } else if constexpr (M == 2) {
        return __int_as_float(__builtin_amdgcn_update_dpp(
            __float_as_int(v), __float_as_int(v), 0x4E, 0xF, 0xF, false));
    } else if constexpr (M == 4) {
        return __int_as_float(__builtin_amdgcn_ds_swizzle(__float_as_int(v), 0x101F));
    } else {
        return __int_as_float(__builtin_amdgcn_ds_swizzle(__float_as_int(v), 0x201F));
    }
}

// ---- fused-conv machinery (verbatim, verified v4..v10) ----
template<int RM, int LQ, bool KEEPD, int BASE>
__device__ __forceinline__ void conv_A(c32 s[16], int sub, PP pp) {
    #pragma unroll
    for (int r = 0; r < 16; ++r) if (r & RM) { s[r].x = sx<LQ>(s[r].x); s[r].y = sx<LQ>(s[r].y); }
    const bool cb = (sub & LQ) != 0;
    const c32 M00 = csel(cb, c32{P(BASE+8),P(BASE+9)},   c32{P(BASE+0),P(BASE+1)});
    const c32 M01 = csel(cb, c32{P(BASE+10),P(BASE+11)}, c32{P(BASE+2),P(BASE+3)});
    const c32 M10 = csel(cb, c32{P(BASE+12),P(BASE+13)}, c32{P(BASE+4),P(BASE+5)});
    const c32 M11 = csel(cb, c32{P(BASE+14),P(BASE+15)}, c32{P(BASE+6),P(BASE+7)});
    #pragma unroll
    for (int r = 0; r < 16; ++r) if (!(r & RM)) {
        c32 lo = s[r], hi = s[r|RM];
        s[r]    = cadd(cmul(M00,lo), cmul(M01,hi));
        s[r|RM] = cadd(cmul(M10,lo), cmul(M11,hi));
    }
    if constexpr (KEEPD) {
        #pragma unroll
        for (int r = 0; r < 16; ++r) if (r & RM) { s[r].x = sx<LQ>(s[r].x); s[r].y = sx<LQ>(s[r].y); }
    }
}

template<int RM, int LQ, int BASE>
__device__ __forceinline__ void conv_B(c32 s[16], int sub, PP pp) {
    const bool cb = (sub & LQ) != 0;
    #pragma unroll
    for (int r = 0; r < 16; ++r) if (!(r & RM)) {
        c32 lo = s[r], hi = s[r|RM];
        s[r]    = csel(cb, hi, lo);
        s[r|RM] = csel(cb, lo, hi);
    }
    const c32 RS0 = csel(cb, c32{P(BASE+6),P(BASE+7)},   c32{P(BASE+0),P(BASE+1)});
    const c32 RP0 = csel(cb, c32{P(BASE+4),P(BASE+5)},   c32{P(BASE+2),P(BASE+3)});
    const c32 RS1 = csel(cb, c32{P(BASE+14),P(BASE+15)}, c32{P(BASE+8),P(BASE+9)});
    const c32 RP1 = csel(cb, c32{P(BASE+12),P(BASE+13)}, c32{P(BASE+10),P(BASE+11)});
    #pragma unroll
    for (int r = 0; r < 16; ++r) {
        c32 pt{ sx<LQ>(s[r].x), sx<LQ>(s[r].y) };
        const c32 RS = (r & RM) ? RS1 : RS0;
        const c32 RP = (r & RM) ? RP1 : RP0;
        s[r] = cadd(cmul(RS, s[r]), cmul(RP, pt));
    }
}

template<int CM, int TM, bool KEEPD, int BASE>
__device__ __forceinline__ void conv_RR(c32 s[16], PP pp) {
    c32 m[2][2][2];
    #pragma unroll
    for (int q = 0; q < 2; ++q)
      #pragma unroll
      for (int i = 0; i < 2; ++i)
        #pragma unroll
        for (int j = 0; j < 2; ++j)
          m[q][i][j] = c32{ P(BASE + q*8 + i*4 + j*2), P(BASE + q*8 + i*4 + j*2 + 1) };
    #pragma unroll
    for (int r = 0; r < 16; ++r) if ((r & TM) && !(r & CM)) { c32 t = s[r]; s[r] = s[r|CM]; s[r|CM] = t; }
    #pragma unroll
    for (int r = 0; r < 16; ++r) if (!(r & TM)) {
        const int q = (r & CM) ? 1 : 0;
        c32 lo = s[r], hi = s[r|TM];
        s[r]    = cadd(cmul(m[q][0][0],lo), cmul(m[q][0][1],hi));
        s[r|TM] = cadd(cmul(m[q][1][0],lo), cmul(m[q][1][1],hi));
    }
    if constexpr (KEEPD) {
        #pragma unroll
        for (int r = 0; r < 16; ++r) if ((r & TM) && !(r & CM)) { c32 t = s[r]; s[r] = s[r|CM]; s[r|CM] = t; }
    }
}

template<int RM, int BASE>
__device__ __forceinline__ void pool_plain(c32 s[16], PP pp) {
    const c32 V00{P(BASE+0),P(BASE+1)}, V01{P(BASE+2),P(BASE+3)};
    const c32 V10{P(BASE+4),P(BASE+5)}, V11{P(BASE+6),P(BASE+7)};
    #pragma unroll
    for (int r = 0; r < 16; ++r) if (!(r & RM)) {
        c32 lo = s[r], hi = s[r|RM];
        s[r]    = cadd(cmul(V00,lo), cmul(V01,hi));
        s[r|RM] = cadd(cmul(V10,lo), cmul(V11,hi));
    }
}
template<int RM, int LQ, int BASE>
__device__ __forceinline__ void pool_lanec(c32 s[16], int sub, PP pp) {
    const bool cb = (sub & LQ) != 0;
    const c32 E00 = csel(cb, c32{P(BASE+2),P(BASE+3)}, c32{P(BASE+0),P(BASE+1)});
    const c32 E01 = csel(cb, c32{P(BASE+0),P(BASE+1)}, c32{P(BASE+2),P(BASE+3)});
    const c32 E10 = csel(cb, c32{P(BASE+6),P(BASE+7)}, c32{P(BASE+4),P(BASE+5)});
    const c32 E11 = csel(cb, c32{P(BASE+4),P(BASE+5)}, c32{P(BASE+6),P(BASE+7)});
    #pragma unroll
    for (int r = 0; r < 16; ++r) if (!(r & RM)) {
        c32 lo = s[r], hi = s[r|RM];
        s[r]    = cadd(cmul(E00,lo), cmul(E01,hi));
        s[r|RM] = cadd(cmul(E10,lo), cmul(E11,hi));
    }
}
template<int RM, int CRM, int BASE>
__device__ __forceinline__ void pool_regc(c32 s[16], PP pp) {
    const c32 V00{P(BASE+0),P(BASE+1)}, V01{P(BASE+2),P(BASE+3)};
    const c32 V10{P(BASE+4),P(BASE+5)}, V11{P(BASE+6),P(BASE+7)};
    #pragma unroll
    for (int r = 0; r < 16; ++r) if (!(r & RM)) {
        const bool swp = (r & CRM) != 0;
        const c32 A = swp ? V01 : V00, Bm = swp ? V00 : V01;
        const c32 C = swp ? V11 : V10, D  = swp ? V10 : V11;
        c32 lo = s[r], hi = s[r|RM];
        s[r]    = cadd(cmul(A,lo),  cmul(Bm,hi));
        s[r|RM] = cadd(cmul(C,lo),  cmul(D,hi));
    }
}

__device__ __forceinline__ float tanh_fast(float x) {
    float e = __expf(2.f * x);
    return (e - 1.f) / (e + 1.f);
}

// ---- K1: in-block param setup + grid eval -> role-major g_R ----
__launch_bounds__(256)
__global__ void qcnn_eval_grid(const float* __restrict__ rz,  const float* __restrict__ ry,
                               const float* __restrict__ ry2, const float* __restrict__ pool) {
    __shared__ float par[256];
    const int tid = threadIdx.x;

    if (tid < 10) {
        const int cc = tid;
        const bool hasD = (cc <= 3) || (cc == 7) || (cc == 8);
        float tz = rz[cc], ta = ry[cc], tb = ry2[cc];
        float cz = __cosf(0.5f*tz), szz = __sinf(0.5f*tz);
        float cp = __cosf(0.5f*(ta+tb)), sp = __sinf(0.5f*(ta+tb));
        float cm = __cosf(0.5f*(ta-tb)), sm = __sinf(0.5f*(ta-tb));
        float A0[2][2] = {{cp,-sp},{sp,cp}};
        float A1[2][2] = {{sm,cm},{cm,-sm}};
        float* o = par + 16*cc;
        #pragma unroll
        for (int which = 0; which < 2; ++which) {
            float px = cz, py = which ? szz : -szz;
            #pragma unroll
            for (int row = 0; row < 2; ++row)
              #pragma unroll
              for (int col = 0; col < 2; ++col) {
                float ex = which ? A1[row][col] : A0[row][col], ey = 0.f;
                if (hasD && col == 1) { ey = -ex; ex = 0.f; }
                o[which*8 + row*4 + col*2 + 0] = px*ex - py*ey;
                o[which*8 + row*4 + col*2 + 1] = px*ey + py*ex;
            }
        }
    } else if (tid < 16) {
        const int pc = tid - 10;
        const bool hasS = (pc <= 2) || (pc == 4);
        float th = pool[3*pc], ph = pool[3*pc+1], la = pool[3*pc+2];
        float ct = __cosf(0.5f*th), st = __sinf(0.5f*th);
        float u[2][2][2] = {
            {{ct, 0.f},                      {-__cosf(la)*st, -__sinf(la)*st}},
            {{__cosf(ph)*st, __sinf(ph)*st}, {__cosf(ph+la)*ct, __sinf(ph+la)*ct}}};
        if (hasS) {
            #pragma unroll
            for (int row = 0; row < 2; ++row) {
                float xx = u[row][1][0], yy = u[row][1][1];
                u[row][1][0] = -yy; u[row][1][1] = xx;
            }
        }
        float* o = par + 160 + 8*pc;
        #pragma unroll
        for (int row = 0; row < 2; ++row)
          #pragma unroll
          for (int col = 0; col < 2; ++col) {
            o[row*4+col*2+0] = u[row][col][0];
            o[row*4+col*2+1] = u[row][col][1];
        }
    } else if (tid < 64) {
        par[208 + (tid - 16)] = 0.f;
    }
    __syncthreads();

    const int lane = tid & 63;
    const int sub  = lane & 15;
    PP pp{ par[lane], par[lane+64], par[lane+128], par[lane+192] };
    const int gwave = (blockIdx.x * blockDim.x + tid) >> 6;
    const int b = gwave * 4 + (lane >> 4);   // all lanes run (no divergent exit)

    const float H = 0.8660254037844386f;
    float cw[8], sw_[8];
    int rr = b;
    #pragma unroll
    for (int w = 0; w < 8; ++w) {
        int t = rr % 3; rr /= 3;
        cw[w]  = (t == 0) ? 1.f : 0.5f;
        sw_[w] = (t == 0) ? 0.f : ((t == 1) ? H : -H);
    }

    float a = ((sub & 8) ? sw_[0] : cw[0]);
    a *= (sub & 1) ? sw_[2] : cw[2];
    a *= (sub & 2) ? sw_[4] : cw[4];
    a *= (sub & 4) ? sw_[6] : cw[6];

    c32 s[16];
    float a13[4] = {cw[1]*cw[3], sw_[1]*cw[3], cw[1]*sw_[3], sw_[1]*sw_[3]};
    float a57[4] = {cw[5]*cw[7], sw_[5]*cw[7], cw[5]*sw_[7], sw_[5]*sw_[7]};
    #pragma unroll
    for (int r = 0; r < 16; ++r) s[r] = c32{ a * a13[r & 3] * a57[r >> 2], 0.f };

    conv_A<1, 8, false,  0>(s, sub, pp);
    conv_A<2, 1, true,  16>(s, sub, pp);
    conv_A<4, 2, true,  32>(s, sub, pp);
    conv_A<8, 4, true,  48>(s, sub, pp);
    conv_B<1, 1, 64>(s, sub, pp);
    conv_B<2, 2, 80>(s, sub, pp);
    conv_B<4, 4, 96>(s, sub, pp);
    pool_lanec<1, 1, 160>(s, sub, pp);
    pool_lanec<2, 2, 168>(s, sub, pp);
    pool_lanec<4, 4, 176>(s, sub, pp);
    pool_plain<8, 184>(s, pp);
    conv_RR<1, 2, false, 112>(s, pp);
    conv_RR<4, 8, true,  128>(s, pp);
    conv_RR<2, 4, false, 144>(s, pp);
    pool_regc<2, 4, 192>(s, pp);
    pool_plain<8, 200>(s, pp);

    float e3 = 0.f, e7 = 0.f;
    #pragma unroll
    for (int r = 0; r < 16; ++r) {
        float p = s[r].x*s[r].x + s[r].y*s[r].y;
        e3 += (r & 2) ? -p : p;
        e7 += (r & 8) ? -p : p;
    }
    e3 += sx<1>(e3); e3 += sx<2>(e3); e3 += sx<4>(e3); e3 += sx<8>(e3);
    e7 += sx<1>(e7); e7 += sx<2>(e7); e7 += sx<4>(e7); e7 += sx<8>(e7);

    if (sub == 0 && b < 6561) {
        // b trits: jj = t0+3t1, t2, t3, aa = t4+3t5, bq = t6+3t7
        int jj = b % 9;
        int t2 = (b / 9) % 3;
        int t3 = (b / 27) % 3;
        int k  = b / 81;
        int aa = k % 9;
        int bq = k / 9;
        // role bq-half: takeLow(t2) covers bq 0..3
        int bh = (bq < 4) ? ((t2 == 1) ? 1 : 0) : ((t2 == 1) ? 0 : 1);
        int c0 = (bh == 0) ? 4 : 5;
        int c1 = (bh == 0) ? 5 : 4;
        int c2 = (bh == 0) ? 4 : 5;
        int baseRows = (t2 == 0) ? 0 : ((t2 == 1) ? 9*c0 : 9*(c0+c1));
        int cnt = (t2 == 0) ? c0 : ((t2 == 1) ? c1 : c2);
        int bqIdx = (bq < 4) ? bq : bq - 4;
        int pos = (baseRows + jj*cnt + bqIdx)*9 + aa;
        g_R[(t3*2 + bh)*1152 + pos]       = e3;   // tt=0 roles: 0..5
        g_R[(6 + t3*2 + bh)*1152 + pos]   = e7;   // tt=1 roles: 6..11
    }
}

// Lagrange cardinal triple at nodes {0, 2pi/3, -2pi/3}
__device__ __forceinline__ void lag3(float xv, float& l0, float& l1, float& l2) {
    const float A = 0.33333333333333333f;
    const float K = 0.57735026918962576f;
    float c = __cosf(xv), s = __sinf(xv);
    l0 = fmaf(2.f * A, c, A);
    float m = A * (1.f - c);
    l1 = fmaf(K, s, m);
    l2 = fmaf(-K, s, m);
}

// ---- pure-VALU contraction over this role's T slice (lane-distributed) ----
template<int BH>
__device__ __forceinline__ void contract(const float (&tr)[18],
                                         const float (&p)[4][9], const float (&q)[4][9],
                                         const float (&g10)[4][9],
                                         const float (&u23)[3][4],
                                         float (&acc)[4]) {
    constexpr int cnts[3] = { (BH==0)?4:5, (BH==0)?5:4, (BH==0)?4:5 };
    int base = 0;   // folded to constants by full unroll
    #pragma unroll
    for (int t2 = 0; t2 < 3; ++t2) {
        const int cnt = cnts[t2];
        const int lo  = ((BH==0) ^ (t2==1)) ? 0 : 4;
        #pragma unroll
        for (int jj = 0; jj < 9; ++jj) {
            float y[4] = {0.f, 0.f, 0.f, 0.f};
            #pragma unroll
            for (int bi = 0; bi < cnt; ++bi) {
                const int row = base + jj*cnt + bi;
                float sv[4] = {0.f, 0.f, 0.f, 0.f};
                #pragma unroll
                for (int a = 0; a < 9; ++a) {
                    const int pos = row*9 + a;
                    const float tv = __uint_as_float(__builtin_amdgcn_readlane(
                        __float_as_uint(tr[pos >> 6]), pos & 63));
                    #pragma unroll
                    for (int e = 0; e < 4; ++e) sv[e] = fmaf(tv, p[e][a], sv[e]);
                }
                #pragma unroll
                for (int e = 0; e < 4; ++e) y[e] = fmaf(q[e][lo + bi], sv[e], y[e]);
            }
            #pragma unroll
            for (int e = 0; e < 4; ++e)
                acc[e] = fmaf(u23[t2][e] * g10[e][jj], y[e], acc[e]);
        }
        base += 9 * cnt;
    }
}

// ---- K2: 768 threads = 12 role-waves; 4 elements/thread; T in registers ----
__launch_bounds__(768, 3)
__global__ void qcnn_apply(const float* __restrict__ x,
                           const float* __restrict__ W1, const float* __restrict__ b1,
                           const float* __restrict__ W2, const float* __restrict__ b2,
                           float* __restrict__ out, int B) {
    __shared__ float Pl[3072];           // 12 partial rows x 256 elements

    const int tid  = threadIdx.x;
    const int lane = tid & 63;
    const int wave = tid >> 6;           // 0..11
    const int tt   = wave & 1;           // tensor: 0 -> e3, 1 -> e7
    const int rest = wave >> 1;
    const int t3   = rest % 3;
    const int bh   = rest / 3;
    const int roleId = tt*6 + t3*2 + bh;

    // --- load this role's T slice into 18 lane-distributed VGPRs ---
    float tr[18];
    #pragma unroll
    for (int kk = 0; kk < 18; ++kk)
        tr[kk] = g_R[roleId*1152 + kk*64 + lane];

    const int gbase = (blockIdx.x * 64 + lane) * 4;

    // --- per-element Lagrange basis (4 elements) ---
    float p[4][9], q[4][9], g10[4][9];
    float u23[3][4];
    #pragma unroll
    for (int e = 0; e < 4; ++e) {
        int idx = gbase + e; if (idx >= B) idx = B - 1;
        const float4 xa = *reinterpret_cast<const float4*>(x + idx*8);
        const float4 xb = *reinterpret_cast<const float4*>(x + idx*8 + 4);
        float l0[3], l1[3], l2[3], l3[3], l4[3], l5[3], l6[3], l7[3];
        lag3(xa.x, l0[0], l0[1], l0[2]);
        lag3(xa.y, l1[0], l1[1], l1[2]);
        lag3(xa.z, l2[0], l2[1], l2[2]);
        lag3(xa.w, l3[0], l3[1], l3[2]);
        lag3(xb.x, l4[0], l4[1], l4[2]);
        lag3(xb.y, l5[0], l5[1], l5[2]);
        lag3(xb.z, l6[0], l6[1], l6[2]);
        lag3(xb.w, l7[0], l7[1], l7[2]);
        #pragma unroll
        for (int u = 0; u < 3; ++u)
          #pragma unroll
          for (int v = 0; v < 3; ++v) {
            g10[e][u + 3*v] = l0[u] * l1[v];   // jj = t0 + 3 t1
            p[e][u + 3*v]   = l4[u] * l5[v];   // a  = t4 + 3 t5
            q[e][u + 3*v]   = l6[u] * l7[v];   // bq = t6 + 3 t7
        }
        const float g3 = (t3 == 0) ? l3[0] : ((t3 == 1) ? l3[1] : l3[2]);
        u23[0][e] = g3 * l2[0];
        u23[1][e] = g3 * l2[1];
        u23[2][e] = g3 * l2[2];
    }

    // --- pure-VALU contraction ---
    float acc[4] = {0.f, 0.f, 0.f, 0.f};
    if (bh == 0) contract<0>(tr, p, q, g10, u23, acc);
    else         contract<1>(tr, p, q, g10, u23, acc);

    // --- combine partials across the 12 role-waves ---
    #pragma unroll
    for (int e = 0; e < 4; ++e) Pl[wave*256 + lane*4 + e] = acc[e];
    __syncthreads();

    if (tid < 256) {
        const int elem = blockIdx.x * 256 + tid;
        if (elem < B) {
            float e3 = 0.f, e7 = 0.f;
            #pragma unroll
            for (int r = 0; r < 6; ++r) {
                e3 += Pl[(2*r)   * 256 + tid];   // waves 0,2,4,6,8,10 = tt0
                e7 += Pl[(2*r+1) * 256 + tid];   // waves 1,3,5,7,9,11 = tt1
            }
            float z = b2[0];
            #pragma unroll
            for (int i = 0; i < 10; ++i) {
                float h = tanh_fast(W1[2*i]*e3 + W1[2*i+1]*e7 + b1[i]);
                z += W2[i]*h;
            }
            out[elem] = 1.f / (1.f + __expf(-z));
        }
    }
}

extern "C" void kernel_launch(void* const* d_in, const int* in_sizes, int n_in,
                              void* d_out, int out_size, void* d_ws, size_t ws_size,
                              hipStream_t stream) {
    const float* x       = (const float*)d_in[0];
    const float* conv_rz = (const float*)d_in[1];
    const float* conv_ry = (const float*)d_in[2];
    const float* conv_ry2= (const float*)d_in[3];
    const float* pool    = (const float*)d_in[4];
    const float* W1      = (const float*)d_in[5];
    const float* b1      = (const float*)d_in[6];
    const float* W2      = (const float*)d_in[7];
    const float* b2      = (const float*)d_in[8];
    float* out = (float*)d_out;
    (void)d_ws; (void)ws_size;

    int B = in_sizes[0] / 8;

    qcnn_eval_grid<<<411, 256, 0, stream>>>(conv_rz, conv_ry, conv_ry2, pool);
    qcnn_apply<<<(B + 255) / 256, 768, 0, stream>>>(x, W1, b1, W2, b2, out, B);
}

// Round 12
// 46.551 us; speedup vs baseline: 1.5356x; 1.5356x over previous
//
#include <hip/hip_runtime.h>
#include <math.h>

// ---------------------------------------------------------------------------
// QCNN 8-qubit statevector, v12: v10 structure (T from global, wave-uniform
// VMEM) with E=2 elements/thread and 512 blocks -> 2 blocks/CU = 6 waves/SIMD
// (v10 was latency-bound at 3 waves/SIMD: VALUBusy 33% = FMA floor / 3).
// v11's readlane contraction REVERTED (readlanes are VALU instrs on the
// critical path -> 2x issue cost; measured regression).
// g_T layout (floats): [0..5831] Tmain t=0 | [5832..11663] Tmain t=1 |
//                      [11664..12635] T8 t=0 | [12636..13607] T8 t=1
// ---------------------------------------------------------------------------

__device__ __align__(16) float g_T[13608];

struct c32 { float x, y; };
__device__ __forceinline__ c32 cmul(c32 a, c32 b){ return c32{a.x*b.x - a.y*b.y, a.x*b.y + a.y*b.x}; }
__device__ __forceinline__ c32 cadd(c32 a, c32 b){ return c32{a.x+b.x, a.y+b.y}; }
__device__ __forceinline__ c32 csel(bool c, c32 a, c32 b){ return c32{c?a.x:b.x, c?a.y:b.y}; }

struct PP { float a, b, c, d; };

__device__ __forceinline__ float pget(int i, PP pp) {
    float s = (i < 64) ? pp.a : (i < 128) ? pp.b : (i < 192) ? pp.c : pp.d;
    return __uint_as_float(__builtin_amdgcn_readlane(__float_as_uint(s), i & 63));
}
#define P(I) pget((I), pp)

template<int M>
__device__ __forceinline__ float sx(float v) {
    if constexpr (M == 1) {
        return __int_as_float(__builtin_amdgcn_update_dpp(
            __float_as_int(v), __float_as_int(v), 0xB1, 0xF, 0xF, false));
    } else if constexpr (M == 2) {
        return __int_as_float(__builtin_amdgcn_update_dpp(
            __float_as_int(v), __float_as_int(v), 0x4E, 0xF, 0xF, false));
    } else if constexpr (M == 4) {
        return __int_as_float(__builtin_amdgcn_ds_swizzle(__float_as_int(v), 0x101F));
    } else {
        return __int_as_float(__builtin_amdgcn_ds_swizzle(__float_as_int(v), 0x201F));
    }
}

// ---- fused-conv machinery (verbatim, verified v4..v10) ----
template<int RM, int LQ, bool KEEPD, int BASE>
__device__ __forceinline__ void conv_A(c32 s[16], int sub, PP pp) {
    #pragma unroll
    for (int r = 0; r < 16; ++r) if (r & RM) { s[r].x = sx<LQ>(s[r].x); s[r].y = sx<LQ>(s[r].y); }
    const bool cb = (sub & LQ) != 0;
    const c32 M00 = csel(cb, c32{P(BASE+8),P(BASE+9)},   c32{P(BASE+0),P(BASE+1)});
    const c32 M01 = csel(cb, c32{P(BASE+10),P(BASE+11)}, c32{P(BASE+2),P(BASE+3)});
    const c32 M10 = csel(cb, c32{P(BASE+12),P(BASE+13)}, c32{P(BASE+4),P(BASE+5)});
    const c32 M11 = csel(cb, c32{P(BASE+14),P(BASE+15)}, c32{P(BASE+6),P(BASE+7)});
    #pragma unroll
    for (int r = 0; r < 16; ++r) if (!(r & RM)) {
        c32 lo = s[r], hi = s[r|RM];
        s[r]    = cadd(cmul(M00,lo), cmul(M01,hi));
        s[r|RM] = cadd(cmul(M10,lo), cmul(M11,hi));
    }
    if constexpr (KEEPD) {
        #pragma unroll
        for (int r = 0; r < 16; ++r) if (r & RM) { s[r].x = sx<LQ>(s[r].x); s[r].y = sx<LQ>(s[r].y); }
    }
}

template<int RM, int LQ, int BASE>
__device__ __forceinline__ void conv_B(c32 s[16], int sub, PP pp) {
    const bool cb = (sub & LQ) != 0;
    #pragma unroll
    for (int r = 0; r < 16; ++r) if (!(r & RM)) {
        c32 lo = s[r], hi = s[r|RM];
        s[r]    = csel(cb, hi, lo);
        s[r|RM] = csel(cb, lo, hi);
    }
    const c32 RS0 = csel(cb, c32{P(BASE+6),P(BASE+7)},   c32{P(BASE+0),P(BASE+1)});
    const c32 RP0 = csel(cb, c32{P(BASE+4),P(BASE+5)},   c32{P(BASE+2),P(BASE+3)});
    const c32 RS1 = csel(cb, c32{P(BASE+14),P(BASE+15)}, c32{P(BASE+8),P(BASE+9)});
    const c32 RP1 = csel(cb, c32{P(BASE+12),P(BASE+13)}, c32{P(BASE+10),P(BASE+11)});
    #pragma unroll
    for (int r = 0; r < 16; ++r) {
        c32 pt{ sx<LQ>(s[r].x), sx<LQ>(s[r].y) };
        const c32 RS = (r & RM) ? RS1 : RS0;
        const c32 RP = (r & RM) ? RP1 : RP0;
        s[r] = cadd(cmul(RS, s[r]), cmul(RP, pt));
    }
}

template<int CM, int TM, bool KEEPD, int BASE>
__device__ __forceinline__ void conv_RR(c32 s[16], PP pp) {
    c32 m[2][2][2];
    #pragma unroll
    for (int q = 0; q < 2; ++q)
      #pragma unroll
      for (int i = 0; i < 2; ++i)
        #pragma unroll
        for (int j = 0; j < 2; ++j)
          m[q][i][j] = c32{ P(BASE + q*8 + i*4 + j*2), P(BASE + q*8 + i*4 + j*2 + 1) };
    #pragma unroll
    for (int r = 0; r < 16; ++r) if ((r & TM) && !(r & CM)) { c32 t = s[r]; s[r] = s[r|CM]; s[r|CM] = t; }
    #pragma unroll
    for (int r = 0; r < 16; ++r) if (!(r & TM)) {
        const int q = (r & CM) ? 1 : 0;
        c32 lo = s[r], hi = s[r|TM];
        s[r]    = cadd(cmul(m[q][0][0],lo), cmul(m[q][0][1],hi));
        s[r|TM] = cadd(cmul(m[q][1][0],lo), cmul(m[q][1][1],hi));
    }
    if constexpr (KEEPD) {
        #pragma unroll
        for (int r = 0; r < 16; ++r) if ((r & TM) && !(r & CM)) { c32 t = s[r]; s[r] = s[r|CM]; s[r|CM] = t; }
    }
}

template<int RM, int BASE>
__device__ __forceinline__ void pool_plain(c32 s[16], PP pp) {
    const c32 V00{P(BASE+0),P(BASE+1)}, V01{P(BASE+2),P(BASE+3)};
    const c32 V10{P(BASE+4),P(BASE+5)}, V11{P(BASE+6),P(BASE+7)};
    #pragma unroll
    for (int r = 0; r < 16; ++r) if (!(r & RM)) {
        c32 lo = s[r], hi = s[r|RM];
        s[r]    = cadd(cmul(V00,lo), cmul(V01,hi));
        s[r|RM] = cadd(cmul(V10,lo), cmul(V11,hi));
    }
}
template<int RM, int LQ, int BASE>
__device__ __forceinline__ void pool_lanec(c32 s[16], int sub, PP pp) {
    const bool cb = (sub & LQ) != 0;
    const c32 E00 = csel(cb, c32{P(BASE+2),P(BASE+3)}, c32{P(BASE+0),P(BASE+1)});
    const c32 E01 = csel(cb, c32{P(BASE+0),P(BASE+1)}, c32{P(BASE+2),P(BASE+3)});
    const c32 E10 = csel(cb, c32{P(BASE+6),P(BASE+7)}, c32{P(BASE+4),P(BASE+5)});
    const c32 E11 = csel(cb, c32{P(BASE+4),P(BASE+5)}, c32{P(BASE+6),P(BASE+7)});
    #pragma unroll
    for (int r = 0; r < 16; ++r) if (!(r & RM)) {
        c32 lo = s[r], hi = s[r|RM];
        s[r]    = cadd(cmul(E00,lo), cmul(E01,hi));
        s[r|RM] = cadd(cmul(E10,lo), cmul(E11,hi));
    }
}
template<int RM, int CRM, int BASE>
__device__ __forceinline__ void pool_regc(c32 s[16], PP pp) {
    const c32 V00{P(BASE+0),P(BASE+1)}, V01{P(BASE+2),P(BASE+3)};
    const c32 V10{P(BASE+4),P(BASE+5)}, V11{P(BASE+6),P(BASE+7)};
    #pragma unroll
    for (int r = 0; r < 16; ++r) if (!(r & RM)) {
        const bool swp = (r & CRM) != 0;
        const c32 A = swp ? V01 : V00, Bm = swp ? V00 : V01;
        const c32 C = swp ? V11 : V10, D  = swp ? V10 : V11;
        c32 lo = s[r], hi = s[r|RM];
        s[r]    = cadd(cmul(A,lo),  cmul(Bm,hi));
        s[r|RM] = cadd(cmul(C,lo),  cmul(D,hi));
    }
}

__device__ __forceinline__ float tanh_fast(float x) {
    float e = __expf(2.f * x);
    return (e - 1.f) / (e + 1.f);
}

// ---- K1: in-block param setup + grid eval, writes g_T (Tmain + T8) ----
__launch_bounds__(256)
__global__ void qcnn_eval_grid(const float* __restrict__ rz,  const float* __restrict__ ry,
                               const float* __restrict__ ry2, const float* __restrict__ pool) {
    __shared__ float par[256];
    const int tid = threadIdx.x;

    if (tid < 10) {
        const int cc = tid;
        const bool hasD = (cc <= 3) || (cc == 7) || (cc == 8);
        float tz = rz[cc], ta = ry[cc], tb = ry2[cc];
        float cz = __cosf(0.5f*tz), szz = __sinf(0.5f*tz);
        float cp = __cosf(0.5f*(ta+tb)), sp = __sinf(0.5f*(ta+tb));
        float cm = __cosf(0.5f*(ta-tb)), sm = __sinf(0.5f*(ta-tb));
        float A0[2][2] = {{cp,-sp},{sp,cp}};
        float A1[2][2] = {{sm,cm},{cm,-sm}};
        float* o = par + 16*cc;
        #pragma unroll
        for (int which = 0; which < 2; ++which) {
            float px = cz, py = which ? szz : -szz;
            #pragma unroll
            for (int row = 0; row < 2; ++row)
              #pragma unroll
              for (int col = 0; col < 2; ++col) {
                float ex = which ? A1[row][col] : A0[row][col], ey = 0.f;
                if (hasD && col == 1) { ey = -ex; ex = 0.f; }
                o[which*8 + row*4 + col*2 + 0] = px*ex - py*ey;
                o[which*8 + row*4 + col*2 + 1] = px*ey + py*ex;
            }
        }
    } else if (tid < 16) {
        const int pc = tid - 10;
        const bool hasS = (pc <= 2) || (pc == 4);
        float th = pool[3*pc], ph = pool[3*pc+1], la = pool[3*pc+2];
        float ct = __cosf(0.5f*th), st = __sinf(0.5f*th);
        float u[2][2][2] = {
            {{ct, 0.f},                      {-__cosf(la)*st, -__sinf(la)*st}},
            {{__cosf(ph)*st, __sinf(ph)*st}, {__cosf(ph+la)*ct, __sinf(ph+la)*ct}}};
        if (hasS) {
            #pragma unroll
            for (int row = 0; row < 2; ++row) {
                float xx = u[row][1][0], yy = u[row][1][1];
                u[row][1][0] = -yy; u[row][1][1] = xx;
            }
        }
        float* o = par + 160 + 8*pc;
        #pragma unroll
        for (int row = 0; row < 2; ++row)
          #pragma unroll
          for (int col = 0; col < 2; ++col) {
            o[row*4+col*2+0] = u[row][col][0];
            o[row*4+col*2+1] = u[row][col][1];
        }
    } else if (tid < 64) {
        par[208 + (tid - 16)] = 0.f;
    }
    __syncthreads();

    const int lane = tid & 63;
    const int sub  = lane & 15;
    PP pp{ par[lane], par[lane+64], par[lane+128], par[lane+192] };
    const int gwave = (blockIdx.x * blockDim.x + tid) >> 6;
    const int b = gwave * 4 + (lane >> 4);   // all lanes run (no divergent exit)

    const float H = 0.8660254037844386f;
    float cw[8], sw_[8];
    int rr = b;
    #pragma unroll
    for (int w = 0; w < 8; ++w) {
        int t = rr % 3; rr /= 3;
        cw[w]  = (t == 0) ? 1.f : 0.5f;
        sw_[w] = (t == 0) ? 0.f : ((t == 1) ? H : -H);
    }

    float a = ((sub & 8) ? sw_[0] : cw[0]);
    a *= (sub & 1) ? sw_[2] : cw[2];
    a *= (sub & 2) ? sw_[4] : cw[4];
    a *= (sub & 4) ? sw_[6] : cw[6];

    c32 s[16];
    float a13[4] = {cw[1]*cw[3], sw_[1]*cw[3], cw[1]*sw_[3], sw_[1]*sw_[3]};
    float a57[4] = {cw[5]*cw[7], sw_[5]*cw[7], cw[5]*sw_[7], sw_[5]*sw_[7]};
    #pragma unroll
    for (int r = 0; r < 16; ++r) s[r] = c32{ a * a13[r & 3] * a57[r >> 2], 0.f };

    conv_A<1, 8, false,  0>(s, sub, pp);
    conv_A<2, 1, true,  16>(s, sub, pp);
    conv_A<4, 2, true,  32>(s, sub, pp);
    conv_A<8, 4, true,  48>(s, sub, pp);
    conv_B<1, 1, 64>(s, sub, pp);
    conv_B<2, 2, 80>(s, sub, pp);
    conv_B<4, 4, 96>(s, sub, pp);
    pool_lanec<1, 1, 160>(s, sub, pp);
    pool_lanec<2, 2, 168>(s, sub, pp);
    pool_lanec<4, 4, 176>(s, sub, pp);
    pool_plain<8, 184>(s, pp);
    conv_RR<1, 2, false, 112>(s, pp);
    conv_RR<4, 8, true,  128>(s, pp);
    conv_RR<2, 4, false, 144>(s, pp);
    pool_regc<2, 4, 192>(s, pp);
    pool_plain<8, 200>(s, pp);

    float e3 = 0.f, e7 = 0.f;
    #pragma unroll
    for (int r = 0; r < 16; ++r) {
        float p = s[r].x*s[r].x + s[r].y*s[r].y;
        e3 += (r & 2) ? -p : p;
        e7 += (r & 8) ? -p : p;
    }
    e3 += sx<1>(e3); e3 += sx<2>(e3); e3 += sx<4>(e3); e3 += sx<8>(e3);
    e7 += sx<1>(e7); e7 += sx<2>(e7); e7 += sx<4>(e7); e7 += sx<8>(e7);

    if (sub == 0 && b < 6561) {
        // j = t0+3t1+9t2+27t3; aa = t4+3t5; bq = t6+3t7
        int j = b % 81, k = b / 81;
        int aa = k % 9, bq = k / 9;
        if (aa < 8) {
            int base = j * 72 + bq * 8 + aa;
            g_T[base]        = e3;
            g_T[5832 + base] = e7;
        } else {
            int base = 11664 + j * 12 + bq;
            g_T[base]       = e3;
            g_T[972 + base] = e7;
        }
    }
}

// ---- apply inner: one (t2,jj) row, bq-subset [B0,B1), 2 elements ----
template<int B0, int B1>
__device__ __forceinline__ void row_dot(const float* __restrict__ Trow,
                                        const float* __restrict__ T8row,
                                        const float (&p)[2][9], const float (&q)[2][9],
                                        float (&y)[2]) {
    float t8v[B1 - B0];
    if constexpr (B0 == 0) {
        const float4 t = *reinterpret_cast<const float4*>(T8row);
        t8v[0] = t.x; t8v[1] = t.y; t8v[2] = t.z; t8v[3] = t.w;
    } else {
        const float4 t = *reinterpret_cast<const float4*>(T8row + 4);
        t8v[0] = t.x; t8v[1] = t.y; t8v[2] = t.z; t8v[3] = t.w;
        t8v[4] = T8row[8];
    }
    #pragma unroll
    for (int b = B0; b < B1; ++b) {
        const float4 T0 = *reinterpret_cast<const float4*>(Trow + b*8);
        const float4 T1 = *reinterpret_cast<const float4*>(Trow + b*8 + 4);
        const float  t8 = t8v[b - B0];
        #pragma unroll
        for (int e = 0; e < 2; ++e) {
            float sacc = T0.x * p[e][0];
            sacc = fmaf(T0.y, p[e][1], sacc);
            sacc = fmaf(T0.z, p[e][2], sacc);
            sacc = fmaf(T0.w, p[e][3], sacc);
            sacc = fmaf(T1.x, p[e][4], sacc);
            sacc = fmaf(T1.y, p[e][5], sacc);
            sacc = fmaf(T1.z, p[e][6], sacc);
            sacc = fmaf(T1.w, p[e][7], sacc);
            sacc = fmaf(t8,   p[e][8], sacc);
            y[e] = fmaf(q[e][b], sacc, y[e]);
        }
    }
}

// Lagrange cardinal triple at nodes {0, 2pi/3, -2pi/3}
__device__ __forceinline__ void lag3(float xv, float& l0, float& l1, float& l2) {
    const float A = 0.33333333333333333f;
    const float K = 0.57735026918962576f;
    float c = __cosf(xv), s = __sinf(xv);
    l0 = fmaf(2.f * A, c, A);
    float m = A * (1.f - c);
    l1 = fmaf(K, s, m);
    l2 = fmaf(-K, s, m);
}

// ---- K2: 768 threads = 12 role-waves; 2 elements/thread; 2 blocks/CU ----
__launch_bounds__(768, 6)
__global__ void qcnn_apply(const float* __restrict__ x,
                           const float* __restrict__ W1, const float* __restrict__ b1,
                           const float* __restrict__ W2, const float* __restrict__ b2,
                           float* __restrict__ out, int B) {
    __shared__ float Pl[1536];           // 12 partial rows x 128 elements

    const int tid  = threadIdx.x;
    const int lane = tid & 63;
    const int wave = tid >> 6;           // 0..11 = role
    const int tt   = wave & 1;           // tensor: 0 -> e3, 1 -> e7
    const int rest = wave >> 1;          // 0..5
    const int t3   = rest % 3;
    const int bh   = rest / 3;           // bq-half (alternates per t2)

    const int gbase = (blockIdx.x * 64 + lane) * 2;

    // --- per-element Lagrange basis (2 elements) ---
    float p[2][9], q[2][9], g10[2][9];
    float g3v[2], L20[2], L21[2], L22[2];
    #pragma unroll
    for (int e = 0; e < 2; ++e) {
        int idx = gbase + e; if (idx >= B) idx = B - 1;
        const float4 xa = *reinterpret_cast<const float4*>(x + idx*8);
        const float4 xb = *reinterpret_cast<const float4*>(x + idx*8 + 4);
        float l0[3], l1[3], l2[3], l3[3], l4[3], l5[3], l6[3], l7[3];
        lag3(xa.x, l0[0], l0[1], l0[2]);
        lag3(xa.y, l1[0], l1[1], l1[2]);
        lag3(xa.z, l2[0], l2[1], l2[2]);
        lag3(xa.w, l3[0], l3[1], l3[2]);
        lag3(xb.x, l4[0], l4[1], l4[2]);
        lag3(xb.y, l5[0], l5[1], l5[2]);
        lag3(xb.z, l6[0], l6[1], l6[2]);
        lag3(xb.w, l7[0], l7[1], l7[2]);
        #pragma unroll
        for (int u = 0; u < 3; ++u)
          #pragma unroll
          for (int v = 0; v < 3; ++v) {
            g10[e][u + 3*v] = l0[u] * l1[v];   // jj = t0 + 3 t1
            p[e][u + 3*v]   = l4[u] * l5[v];   // a  = t4 + 3 t5
            q[e][u + 3*v]   = l6[u] * l7[v];   // bq = t6 + 3 t7
        }
        g3v[e] = (t3 == 0) ? l3[0] : ((t3 == 1) ? l3[1] : l3[2]);
        L20[e] = l2[0]; L21[e] = l2[1]; L22[e] = l2[2];
    }

    // wave-uniform T bases
    const int tmBase = __builtin_amdgcn_readfirstlane(tt * 5832 + t3 * 1944);
    const int t8Base = __builtin_amdgcn_readfirstlane(11664 + tt * 972 + t3 * 324);

    // --- contraction over this role's slice ---
    float acc[2] = {0.f, 0.f};
    #pragma unroll
    for (int t2 = 0; t2 < 3; ++t2) {
        float u23[2];
        #pragma unroll
        for (int e = 0; e < 2; ++e) {
            float g2 = (t2 == 0) ? L20[e] : ((t2 == 1) ? L21[e] : L22[e]);
            u23[e] = g3v[e] * g2;
        }
        const float* Tt2  = g_T + tmBase + t2 * 648;
        const float* T8t2 = g_T + t8Base + t2 * 108;
        const bool takeLow = (bh == 0) ^ (t2 == 1);   // balance: 13 vs 14 rows
        #pragma unroll
        for (int jj = 0; jj < 9; ++jj) {
            float y[2] = {0.f, 0.f};
            if (takeLow) row_dot<0, 4>(Tt2 + jj*72, T8t2 + jj*12, p, q, y);
            else         row_dot<4, 9>(Tt2 + jj*72, T8t2 + jj*12, p, q, y);
            #pragma unroll
            for (int e = 0; e < 2; ++e)
                acc[e] = fmaf(u23[e] * g10[e][jj], y[e], acc[e]);
        }
    }

    // --- combine partials across the 12 role-waves ---
    #pragma unroll
    for (int e = 0; e < 2; ++e) Pl[wave*128 + lane*2 + e] = acc[e];
    __syncthreads();

    if (tid < 128) {
        const int elem = blockIdx.x * 128 + tid;
        if (elem < B) {
            float e3 = 0.f, e7 = 0.f;
            #pragma unroll
            for (int r = 0; r < 6; ++r) {
                e3 += Pl[(2*r)   * 128 + tid];
                e7 += Pl[(2*r+1) * 128 + tid];
            }
            float z = b2[0];
            #pragma unroll
            for (int i = 0; i < 10; ++i) {
                float h = tanh_fast(W1[2*i]*e3 + W1[2*i+1]*e7 + b1[i]);
                z += W2[i]*h;
            }
            out[elem] = 1.f / (1.f + __expf(-z));
        }
    }
}

extern "C" void kernel_launch(void* const* d_in, const int* in_sizes, int n_in,
                              void* d_out, int out_size, void* d_ws, size_t ws_size,
                              hipStream_t stream) {
    const float* x       = (const float*)d_in[0];
    const float* conv_rz = (const float*)d_in[1];
    const float* conv_ry = (const float*)d_in[2];
    const float* conv_ry2= (const float*)d_in[3];
    const float* pool    = (const float*)d_in[4];
    const float* W1      = (const float*)d_in[5];
    const float* b1      = (const float*)d_in[6];
    const float* W2      = (const float*)d_in[7];
    const float* b2      = (const float*)d_in[8];
    float* out = (float*)d_out;
    (void)d_ws; (void)ws_size;

    int B = in_sizes[0] / 8;

    qcnn_eval_grid<<<411, 256, 0, stream>>>(conv_rz, conv_ry, conv_ry2, pool);
    qcnn_apply<<<(B + 127) / 128, 768, 0, stream>>>(x, W1, b1, W2, b2, out, B);
}